// Round 9
// baseline (18765.759 us; speedup 1.0000x reference)
//
#include <hip/hip_runtime.h>
#include <math.h>

#define B_  32
#define D_  1000
#define Q_  50
#define E_  384
#define H_  384
#define G3_ 1152
#define C_  10
#define GD_ 24      // WGs per direction in persistent GRU
#define JW_ 16      // j-slice per WG (GD_*JW_ == H_)

typedef _Float16 f16;
typedef f16 f16x2 __attribute__((ext_vector_type(2)));
typedef f16 f16x4 __attribute__((ext_vector_type(4)));

__device__ __forceinline__ float dot2f(f16x2 a, f16x2 b, float c) {
#if __has_builtin(__builtin_amdgcn_fdot2)
  return __builtin_amdgcn_fdot2(a, b, c, false);
#else
  return fmaf((float)a.x, (float)b.x, fmaf((float)a.y, (float)b.y, c));
#endif
}
__device__ __forceinline__ f16x2 bc2(unsigned u) { return __builtin_bit_cast(f16x2, u); }

// ---------------- pack Whh_f/Whh_b/Wih_f/Wih_b -> f16 row-major ----------------
__global__ __launch_bounds__(256) void k_packw2(const float* __restrict__ a0,
                                                const float* __restrict__ a1,
                                                const float* __restrict__ a2,
                                                const float* __restrict__ a3,
                                                f16* __restrict__ WQhh,
                                                f16* __restrict__ WQih) {
  const int n4 = G3_ * H_ / 4;                 // 110592 float4 per plane
  int i = blockIdx.x * 256 + threadIdx.x;
  if (i >= n4) return;
  int y = blockIdx.y;
  const float* src = (y == 0) ? a0 : (y == 1) ? a1 : (y == 2) ? a2 : a3;
  f16* dst = (y < 2) ? (WQhh + (size_t)y * G3_ * H_) : (WQih + (size_t)(y - 2) * G3_ * H_);
  float4 v = *(const float4*)(src + (size_t)i * 4);
  f16x4 o; o[0] = (f16)v.x; o[1] = (f16)v.y; o[2] = (f16)v.z; o[3] = (f16)v.w;
  *(f16x4*)(dst + (size_t)i * 4) = o;
}

// ---------------- fused gather+projection: block = 64 rows x all 1152 g ----------------
// Static LDS 61.7 KB (A 64x386 f16 + W-chunk 16x386 f16); 2x2 micro-tile,
// k cached in registers 8 pairs at a time.
__global__ __launch_bounds__(256) void k_projx2(
    const int* __restrict__ toks, const int* __restrict__ lens, int T, int CT, int c,
    const float* __restrict__ emb, const f16* __restrict__ WQih,
    const float* __restrict__ bih_f, const float* __restrict__ bih_b,
    float* __restrict__ outbuf) {
  int dir = blockIdx.y;
  const f16* W = WQih + (size_t)dir * G3_ * E_;
  const float* bias = dir ? bih_b : bih_f;
  float* Cout = outbuf + (size_t)dir * B_ * CT * G3_;
  int nrows = B_ * CT;
  int r0 = blockIdx.x * 64;
  int tid = threadIdx.x;

  __shared__ f16 Als[64][386];   // stride 193 f16x2 -> conflict-free
  __shared__ f16 Wls[16][386];

  // stage A once: 64 rows x 192 pairs, f32->f16 (fused embedding gather)
  for (int it = 0; it < 48; ++it) {
    int slot = tid + 256 * it;                 // 12288
    int rr = slot / 192, pp = slot % 192;
    int row = r0 + rr; if (row >= nrows) row = nrows - 1;
    int b = row / CT, sl = row % CT;
    int s = c * CT + sl;
    int len = lens[b];
    int pos = dir ? (len - 1 - s) : s;
    if (pos < 0) pos = 0;
    if (pos >= T) pos = T - 1;
    const float2 v = *(const float2*)(emb + (size_t)toks[b * T + pos] * E_ + pp * 2);
    f16x2 h2; h2[0] = (f16)v.x; h2[1] = (f16)v.y;
    *(f16x2*)&Als[rr][pp * 2] = h2;
  }

  int r2 = tid >> 3;        // 0..31 -> rows r2*2 + i
  int g2 = tid & 7;         // 0..7  -> gs  g2*2 + j

  for (int g0 = 0; g0 < G3_; g0 += 16) {
    __syncthreads();        // previous chunk's dots done (also covers A staging)
    for (int it = 0; it < 12; ++it) {
      int slot = tid + 256 * it;               // 3072 = 16 rows x 192 pairs
      int rr = slot / 192, pp = slot % 192;
      unsigned u = *(const unsigned*)(W + (size_t)(g0 + rr) * E_ + pp * 2);
      *(unsigned*)&Wls[rr][pp * 2] = u;
    }
    __syncthreads();

    float acc[2][2] = {};
    for (int kb = 0; kb < 192; kb += 8) {
      f16x2 a[2][8], w[2][8];
      #pragma unroll
      for (int kk = 0; kk < 8; ++kk) {
        a[0][kk] = *(const f16x2*)&Als[r2 * 2    ][(kb + kk) * 2];
        a[1][kk] = *(const f16x2*)&Als[r2 * 2 + 1][(kb + kk) * 2];
        w[0][kk] = *(const f16x2*)&Wls[g2 * 2    ][(kb + kk) * 2];
        w[1][kk] = *(const f16x2*)&Wls[g2 * 2 + 1][(kb + kk) * 2];
      }
      #pragma unroll
      for (int kk = 0; kk < 8; ++kk) {
        acc[0][0] = dot2f(a[0][kk], w[0][kk], acc[0][0]);
        acc[0][1] = dot2f(a[0][kk], w[1][kk], acc[0][1]);
        acc[1][0] = dot2f(a[1][kk], w[0][kk], acc[1][0]);
        acc[1][1] = dot2f(a[1][kk], w[1][kk], acc[1][1]);
      }
    }

    #pragma unroll
    for (int i = 0; i < 2; ++i) {
      int row = r0 + r2 * 2 + i;
      if (row < nrows) {
        int g = g0 + g2 * 2;
        float2 o = {acc[i][0] + bias[g], acc[i][1] + bias[g + 1]};
        *(float2*)(Cout + (size_t)row * G3_ + g) = o;
      }
    }
  }
}

// ---------------- persistent GRU: j-split, LDS-resident weights ----------------
// h exchanged via DOUBLE-BUFFERED global mirror: step s reads buf[(s0+s)&1],
// writes buf[(s0+s+1)&1] -> one global barrier per step suffices.
// xw for step s+1 is prefetched BEFORE the step-s barrier (latency hides in spin).
__global__ __launch_bounds__(256) void k_grup(
    const float* __restrict__ xw, int CTloc, int T, int s0, int cnt, int init,
    const f16* __restrict__ WQhh,
    const float* __restrict__ bhhf, const float* __restrict__ bhhb,
    const int* __restrict__ lens,
    f16* __restrict__ hglob, float* __restrict__ hcarF,
    float* __restrict__ outbase, int* __restrict__ ctr) {
  int dir = blockIdx.x / GD_;
  int wgi = blockIdx.x % GD_;
  int j0 = wgi * JW_;
  int tid = threadIdx.x;
  int wv = tid >> 6;
  int lane = tid & 63;
  int b = lane >> 1, ih = lane & 1;
  int jbase = j0 + wv * 4;
  int len = lens[b];
  const float* bhh = dir ? bhhb : bhhf;

  __shared__ __align__(16) f16 wlds[3 * JW_ * H_];   // 36 KB
  __shared__ int sbail;
  #pragma unroll
  for (int it = 0; it < 9; ++it) {
    int slot = tid + 256 * it;                 // 2304 = 48 rows x 48 16B-chunks
    int r = slot / 48, cc = slot % 48;
    int g = r >> 4, jl = r & 15;
    const f16* src = WQhh + ((size_t)dir * G3_ + g * H_ + j0 + jl) * H_ + cc * 8;
    *(uint4*)&wlds[(size_t)r * H_ + cc * 8] = *(const uint4*)src;
  }
  if (tid == 0) sbail = 0;

  float bj[3][4];
  #pragma unroll
  for (int g = 0; g < 3; ++g)
    #pragma unroll
    for (int jj = 0; jj < 4; ++jj) bj[g][jj] = bhh[g * H_ + jbase + jj];

  float hold[4];
  #pragma unroll
  for (int jj = 0; jj < 4; ++jj)
    hold[jj] = init ? 0.f : hcarF[((size_t)dir * B_ + b) * H_ + jbase + jj];

  f16* h0 = hglob + ((size_t)dir * B_ + b) * H_;     // buf0 slice; buf1 at +2*B_*H_
  float* outp = outbase + (size_t)b * T * 2 * H_ + dir * H_;
  const float* xwb = xw + ((size_t)dir * B_ + b) * CTloc * G3_;
  __syncthreads();

  // prologue: prefetch xw for sl=0
  float4 xwv[3];
  if (ih == 0 && cnt > 0 && s0 < len) {
    const float* xp = xwb;
    #pragma unroll
    for (int g = 0; g < 3; ++g) xwv[g] = *(const float4*)(xp + g * H_ + jbase);
  }

  for (int sl = 0; sl < cnt; ++sl) {
    int s = s0 + sl;
    bool alive = (s < len);
    int pos = dir ? (len - 1 - s) : s;
    bool hz = (init && sl == 0);
    int rp = (s0 + sl) & 1;

    uint4 hv[24];
    if (!hz) {
      const f16* hsrc = h0 + (size_t)rp * 2 * B_ * H_ + ih * 192;
      #pragma unroll
      for (int cc = 0; cc < 24; ++cc) hv[cc] = *(const uint4*)(hsrc + cc * 8);
    }

    float accs[3][4];
    #pragma unroll
    for (int g = 0; g < 3; ++g) {
      #pragma unroll
      for (int jj = 0; jj < 4; ++jj) {
        float acc = 0.f;
        if (!hz) {
          const uint4* wp = (const uint4*)&wlds[(size_t)(g * JW_ + wv * 4 + jj) * H_ + ih * 192];
          #pragma unroll
          for (int cc = 0; cc < 24; ++cc) {
            uint4 w4 = wp[cc];
            acc = dot2f(bc2(w4.x), bc2(hv[cc].x), acc);
            acc = dot2f(bc2(w4.y), bc2(hv[cc].y), acc);
            acc = dot2f(bc2(w4.z), bc2(hv[cc].z), acc);
            acc = dot2f(bc2(w4.w), bc2(hv[cc].w), acc);
          }
        }
        float oth = __shfl_xor(acc, 1, 64);
        accs[g][jj] = acc + oth;
      }
    }

    if (ih == 0) {
      if (alive) {
        float xq[3][4];
        #pragma unroll
        for (int g = 0; g < 3; ++g) {
          xq[g][0] = xwv[g].x; xq[g][1] = xwv[g].y; xq[g][2] = xwv[g].z; xq[g][3] = xwv[g].w;
        }
        #pragma unroll
        for (int jj = 0; jj < 4; ++jj) {
          float r = 1.f / (1.f + expf(-(xq[0][jj] + bj[0][jj] + accs[0][jj])));
          float z = 1.f / (1.f + expf(-(xq[1][jj] + bj[1][jj] + accs[1][jj])));
          float n = tanhf(xq[2][jj] + r * (bj[2][jj] + accs[2][jj]));
          hold[jj] = (1.f - z) * n + z * hold[jj];
        }
        float4 o4 = {hold[0], hold[1], hold[2], hold[3]};
        *(float4*)(outp + (size_t)pos * 2 * H_ + jbase) = o4;
      }
      // ALWAYS publish h (frozen batches re-publish) into the write buffer
      f16x4 h16; h16[0] = (f16)hold[0]; h16[1] = (f16)hold[1];
      h16[2] = (f16)hold[2]; h16[3] = (f16)hold[3];
      *(f16x4*)(h0 + (size_t)(rp ^ 1) * 2 * B_ * H_ + jbase) = h16;

      // prefetch xw for sl+1 BEFORE the barrier: latency hides under the spin
      if (sl + 1 < cnt && s + 1 < len) {
        const float* xp = xwb + (size_t)(sl + 1) * G3_;
        #pragma unroll
        for (int g = 0; g < 3; ++g) xwv[g] = *(const float4*)(xp + g * H_ + jbase);
      }
    }

    // one global step-barrier per direction
    __threadfence();
    __syncthreads();
    if (tid == 0) {
      __hip_atomic_fetch_add(&ctr[dir], 1, __ATOMIC_RELEASE, __HIP_MEMORY_SCOPE_AGENT);
      if (!sbail) {
        int tgt = GD_ * (sl + 1);
        // fast path: bare poll (common case: WGs nearly in lockstep)
        int ok = 0;
        for (int k = 0; k < 64; ++k) {
          if (__hip_atomic_load(&ctr[dir], __ATOMIC_RELAXED, __HIP_MEMORY_SCOPE_AGENT) >= tgt) { ok = 1; break; }
        }
        if (!ok) {
          long itc = 0;
          while (__hip_atomic_load(&ctr[dir], __ATOMIC_RELAXED, __HIP_MEMORY_SCOPE_AGENT) < tgt) {
            __builtin_amdgcn_s_sleep(1);
            if (++itc > 5000000L) { sbail = 1; break; }   // sticky fail-fast
          }
        }
      }
    }
    __syncthreads();
    __threadfence();
  }

  if (ih == 0) {
    #pragma unroll
    for (int jj = 0; jj < 4; ++jj)
      hcarF[((size_t)dir * B_ + b) * H_ + jbase + jj] = hold[jj];
  }
}

// ---------------- M[b,d,q] = dot(dos[b,d,:], qos[b,q,:]) ----------------
__global__ __launch_bounds__(256) void k_scores(const float* __restrict__ dos,
                                                const float* __restrict__ qos,
                                                const int* __restrict__ dlen,
                                                const int* __restrict__ qlen,
                                                float* __restrict__ M) {
  int b = blockIdx.x, d0 = blockIdx.y * 64;
  if (d0 >= dlen[b]) return;
  __shared__ float Ds[64][65];
  __shared__ float Qs[50][65];
  int tid = threadIdx.x;
  int lane = tid & 63, qg = tid >> 6;
  float acc[13];
  #pragma unroll
  for (int i = 0; i < 13; ++i) acc[i] = 0.f;
  for (int kc = 0; kc < 2 * H_; kc += 64) {
    #pragma unroll
    for (int i = 0; i < 16; ++i) {
      int lin = tid + 256 * i;
      int rr = lin >> 6, cc = lin & 63;
      int dd = d0 + rr; if (dd >= D_) dd = D_ - 1;
      Ds[rr][cc] = dos[((size_t)b * D_ + dd) * (2 * H_) + kc + cc];
    }
    #pragma unroll
    for (int i = 0; i < 13; ++i) {
      int lin = tid + 256 * i;
      if (lin < 3200) {
        int rr = lin >> 6, cc = lin & 63;
        Qs[rr][cc] = qos[((size_t)b * Q_ + rr) * (2 * H_) + kc + cc];
      }
    }
    __syncthreads();
    #pragma unroll 8
    for (int kk = 0; kk < 64; ++kk) {
      float dv = Ds[lane][kk];
      #pragma unroll
      for (int i = 0; i < 13; ++i) {
        int q = qg + 4 * i;
        if (q < 50) acc[i] = fmaf(dv, Qs[q][kk], acc[i]);
      }
    }
    __syncthreads();
  }
  if (d0 + lane < D_) {
    #pragma unroll
    for (int i = 0; i < 13; ++i) {
      int q = qg + 4 * i;
      if (q < 50) M[((size_t)b * D_ + d0 + lane) * 50 + q] = acc[i];
    }
  }
}

// ---------------- row stats (beta softmax over q) ----------------
__global__ __launch_bounds__(256) void k_rowstats(const float* __restrict__ M,
                                                  const int* __restrict__ dlen,
                                                  const int* __restrict__ qlen,
                                                  float* __restrict__ rowmax,
                                                  float* __restrict__ rowsum) {
  int b = blockIdx.x;
  int d = blockIdx.y * 256 + threadIdx.x;
  if (d >= dlen[b]) return;
  int ql = qlen[b];
  const float* row = M + ((size_t)b * D_ + d) * 50;
  float m = 0.f;
  for (int q = 0; q < ql; ++q) m = fmaxf(m, row[q]);
  float s = 0.f;
  for (int q = 0; q < ql; ++q) s += expf(row[q] - m);
  rowmax[b * D_ + d] = m;
  rowsum[b * D_ + d] = s;
}

// ---------------- col stats (alpha softmax over d) + avg_beta ----------------
__global__ __launch_bounds__(256) void k_colstats(const float* __restrict__ M,
                                                  const int* __restrict__ dlen,
                                                  const int* __restrict__ qlen,
                                                  const float* __restrict__ rowmax,
                                                  const float* __restrict__ rowsum,
                                                  float* __restrict__ colmax,
                                                  float* __restrict__ colsum,
                                                  float* __restrict__ avg_beta) {
  int b = blockIdx.x, q = blockIdx.y;
  if (q >= qlen[b]) return;
  int dl = dlen[b];
  int tid = threadIdx.x;
  __shared__ float red[4];
  __shared__ float r1[4], r2[4];
  float m = 0.f;
  for (int d = tid; d < dl; d += 256) m = fmaxf(m, M[((size_t)b * D_ + d) * 50 + q]);
  for (int o = 32; o > 0; o >>= 1) m = fmaxf(m, __shfl_down(m, o, 64));
  if ((tid & 63) == 0) red[tid >> 6] = m;
  __syncthreads();
  m = fmaxf(fmaxf(red[0], red[1]), fmaxf(red[2], red[3]));
  float s1 = 0.f, s2 = 0.f;
  for (int d = tid; d < dl; d += 256) {
    float v = M[((size_t)b * D_ + d) * 50 + q];
    s1 += expf(v - m);
    s2 += expf(v - rowmax[b * D_ + d]) / (rowsum[b * D_ + d] + 1e-12f);
  }
  for (int o = 32; o > 0; o >>= 1) {
    s1 += __shfl_down(s1, o, 64);
    s2 += __shfl_down(s2, o, 64);
  }
  if ((tid & 63) == 0) { r1[tid >> 6] = s1; r2[tid >> 6] = s2; }
  __syncthreads();
  if (tid == 0) {
    colmax[b * 50 + q] = m;
    colsum[b * 50 + q] = r1[0] + r1[1] + r1[2] + r1[3];
    avg_beta[b * 50 + q] = (r2[0] + r2[1] + r2[2] + r2[3]) / (float)dl;
  }
}

// ---------------- s[b,d] = sum_q alpha * avg_beta ----------------
__global__ __launch_bounds__(256) void k_svec(const float* __restrict__ M,
                                              const int* __restrict__ dlen,
                                              const int* __restrict__ qlen,
                                              const float* __restrict__ colmax,
                                              const float* __restrict__ colsum,
                                              const float* __restrict__ avg_beta,
                                              float* __restrict__ svec) {
  int b = blockIdx.x;
  int d = blockIdx.y * 256 + threadIdx.x;
  if (d >= dlen[b]) return;
  int ql = qlen[b];
  const float* row = M + ((size_t)b * D_ + d) * 50;
  float s = 0.f;
  for (int q = 0; q < ql; ++q)
    s += expf(row[q] - colmax[b * 50 + q]) / (colsum[b * 50 + q] + 1e-12f) * avg_beta[b * 50 + q];
  svec[b * D_ + d] = s;
}

// ---------------- candidate pointer-sum ----------------
__global__ __launch_bounds__(256) void k_pointer(const int* __restrict__ docs,
                                                 const int* __restrict__ cand,
                                                 const int* __restrict__ dlen,
                                                 const float* __restrict__ svec,
                                                 float* __restrict__ out) {
  int b = blockIdx.x, tid = threadIdx.x;
  __shared__ int cs[C_];
  __shared__ float accs[C_];
  if (tid < C_) { cs[tid] = cand[b * C_ + tid]; accs[tid] = 0.f; }
  __syncthreads();
  float loc[C_];
  #pragma unroll
  for (int c = 0; c < C_; ++c) loc[c] = 0.f;
  int dl = dlen[b];
  for (int d = tid; d < dl; d += 256) {
    int t = docs[b * D_ + d];
    float sv = svec[b * D_ + d];
    #pragma unroll
    for (int c = 0; c < C_; ++c)
      if (t == cs[c]) loc[c] += sv;
  }
  #pragma unroll
  for (int c = 0; c < C_; ++c)
    if (loc[c] != 0.f) atomicAdd(&accs[c], loc[c]);
  __syncthreads();
  if (tid < C_) out[b * C_ + tid] = accs[tid];
}

extern "C" void kernel_launch(void* const* d_in, const int* in_sizes, int n_in,
                              void* d_out, int out_size, void* d_ws, size_t ws_size,
                              hipStream_t stream) {
  const int* docs_input   = (const int*)d_in[0];
  const int* docs_len     = (const int*)d_in[1];
  const int* querys_input = (const int*)d_in[2];
  const int* querys_len   = (const int*)d_in[3];
  const int* candidates   = (const int*)d_in[4];
  const float* emb   = (const float*)d_in[5];
  const float* Wih_f = (const float*)d_in[6];
  const float* Whh_f = (const float*)d_in[7];
  const float* bih_f = (const float*)d_in[8];
  const float* bhh_f = (const float*)d_in[9];
  const float* Wih_b = (const float*)d_in[10];
  const float* Whh_b = (const float*)d_in[11];
  const float* bih_b = (const float*)d_in[12];
  const float* bhh_b = (const float*)d_in[13];
  float* out = (float*)d_out;

  float* ws = (float*)d_ws;
  size_t off = 0;
  auto alloc = [&](size_t n) { float* p = ws + off; off += n; return p; };

  f16* WQhh = (f16*)alloc((size_t)G3_ * H_);            // 2 dirs f16
  f16* WQih = (f16*)alloc((size_t)G3_ * H_);
  f16* hgD  = (f16*)alloc((size_t)2 * B_ * H_);         // [2 buf][2 dir][32][384] f16
  f16* hgQ  = (f16*)alloc((size_t)2 * B_ * H_);
  float* hcD = alloc((size_t)2 * B_ * H_);
  float* hcQ = alloc((size_t)2 * B_ * H_);
  int* ctr = (int*)alloc(16);
  float* xwQ = alloc((size_t)2 * B_ * Q_ * G3_);
  float* qos = alloc((size_t)B_ * Q_ * 2 * H_);
  float* dos = alloc((size_t)B_ * D_ * 2 * H_);
  float* Mm  = alloc((size_t)B_ * D_ * 50);
  float* rowmax = alloc((size_t)B_ * D_);
  float* rowsum = alloc((size_t)B_ * D_);
  float* colmax = alloc((size_t)B_ * 50);
  float* colsum = alloc((size_t)B_ * 50);
  float* avgb   = alloc((size_t)B_ * 50);
  float* svec   = alloc((size_t)B_ * D_);

  const int cts[8] = {1000, 500, 250, 125, 50, 25, 10, 5};
  int CT = 5;
  for (int i = 0; i < 8; ++i) {
    size_t need = (off + (size_t)2 * B_ * cts[i] * G3_) * sizeof(float);
    if (need <= ws_size) { CT = cts[i]; break; }
  }
  float* xwD = alloc((size_t)2 * B_ * CT * G3_);
  int NC = (D_ + CT - 1) / CT;

  hipMemsetAsync(ctr, 0, 64, stream);
  k_packw2<<<dim3((G3_ * H_ / 4 + 255) / 256, 4), 256, 0, stream>>>(
      Whh_f, Whh_b, Wih_f, Wih_b, WQhh, WQih);

  // queries (single chunk)
  k_projx2<<<dim3(B_ * Q_ / 64, 2), 256, 0, stream>>>(
      querys_input, querys_len, Q_, Q_, 0, emb, WQih, bih_f, bih_b, xwQ);
  k_grup<<<2 * GD_, 256, 0, stream>>>(xwQ, Q_, Q_, 0, Q_, 1, WQhh, bhh_f, bhh_b,
                                      querys_len, hgQ, hcQ, qos, ctr + 2);

  // docs (chunked timeline; NC==1 when workspace allows)
  for (int c = 0; c < NC; ++c) {
    int s0 = c * CT;
    int cntC = D_ - s0; if (cntC > CT) cntC = CT;
    k_projx2<<<dim3(B_ * CT / 64, 2), 256, 0, stream>>>(
        docs_input, docs_len, D_, CT, c, emb, WQih, bih_f, bih_b, xwD);
    if (c > 0) hipMemsetAsync(ctr, 0, 8, stream);
    k_grup<<<2 * GD_, 256, 0, stream>>>(xwD, CT, D_, s0, cntC, (c == 0) ? 1 : 0,
                                        WQhh, bhh_f, bhh_b, docs_len, hgD, hcD, dos, ctr);
  }

  k_scores<<<dim3(B_, (D_ + 63) / 64), 256, 0, stream>>>(dos, qos, docs_len, querys_len, Mm);
  k_rowstats<<<dim3(B_, (D_ + 255) / 256), 256, 0, stream>>>(Mm, docs_len, querys_len, rowmax, rowsum);
  k_colstats<<<dim3(B_, 50), 256, 0, stream>>>(Mm, docs_len, querys_len, rowmax, rowsum,
                                               colmax, colsum, avgb);
  k_svec<<<dim3(B_, (D_ + 255) / 256), 256, 0, stream>>>(Mm, docs_len, querys_len,
                                                         colmax, colsum, avgb, svec);
  k_pointer<<<B_, 256, 0, stream>>>(docs_input, candidates, docs_len, svec, out);
}